// Round 6
// baseline (202.206 us; speedup 1.0000x reference)
//
#include <hip/hip_runtime.h>
#include <stdint.h>

#define BB 4
#define SS 4096
#define DD 1024
#define FF 4096
#define CAP 512
#define MTOT (BB*CAP)          // 2048
#define NOUT (BB*SS*DD)        // 16777216

typedef unsigned short ushort_t;
typedef float  float4v  __attribute__((ext_vector_type(4)));
typedef short  short8v  __attribute__((ext_vector_type(8)));
typedef unsigned short ushort4v __attribute__((ext_vector_type(4)));

// ws layout (bytes)
#define OFF_RW   0u             // B*S f32 = 64KB
#define OFF_IDX  (64u*1024u)    // 2048 int = 8KB
#define OFF_WTOP (72u*1024u)    // 2048 f32 = 8KB
#define OFF_ACC  (80u*1024u)    // 4B loss accumulator
#define OFF_POS  (128u*1024u)   // B*S int = 64KB (row -> compact slot or -1)
#define OFF_A    (1u<<20)       // MTOT*D bf16 = 4MB
#define OFF_W1T  (5u<<20)       // F*D bf16 = 8MB; REUSED as O (MTOT*D f32 = 8MB) after GEMM1
#define OFF_W2T  (13u<<20)      // D*F bf16 = 8MB
#define OFF_H    (21u<<20)      // MTOT*F bf16 = 16MB (ends 37MB)

#define GLD16(gsrc, ldst) __builtin_amdgcn_global_load_lds( \
    (const __attribute__((address_space(1))) void*)(gsrc),  \
    (__attribute__((address_space(3))) void*)(ldst), 16, 0, 0)

__device__ inline ushort_t f2bf(float f) {
  uint32_t u = __builtin_bit_cast(uint32_t, f);
  u = u + 0x7fffu + ((u >> 16) & 1u);
  return (ushort_t)(u >> 16);
}

// ---------------- router: rw = sigmoid(x . w) ----------------
__global__ void router_kernel(const float* __restrict__ x, const float* __restrict__ w,
                              float* __restrict__ rw) {
  int wave = threadIdx.x >> 6;
  int lane = threadIdx.x & 63;
  int row  = blockIdx.x * 4 + wave;            // [0, B*S)
  const float4* xr = (const float4*)(x + (size_t)row * DD);
  const float4* wr = (const float4*)w;
  float s = 0.f;
#pragma unroll
  for (int i = 0; i < 4; i++) {
    float4 a = xr[lane + i * 64];
    float4 b = wr[lane + i * 64];
    s += a.x * b.x + a.y * b.y + a.z * b.z + a.w * b.w;
  }
#pragma unroll
  for (int off = 32; off > 0; off >>= 1) s += __shfl_xor(s, off, 64);
  if (lane == 0) rw[row] = 1.f / (1.f + expf(-s));
}

// ---------------- topk + order + w_top + posmap + BCE loss ----------------
__global__ __launch_bounds__(1024) void topk_kernel(const float* __restrict__ rw,
                                                    int* __restrict__ idxs,
                                                    float* __restrict__ wtop,
                                                    int* __restrict__ posmap,
                                                    float* __restrict__ acc) {
  __shared__ float v[SS];
  __shared__ int   id[SS];
  __shared__ int   seq2[CAP];
  __shared__ int   rank2[CAP];
  __shared__ unsigned char sel[SS];
  __shared__ float wsum[16];
  const int b = blockIdx.x, tid = threadIdx.x;
  const float* rwg = rw + (size_t)b * SS;
  for (int m = tid; m < SS; m += 1024) {
    v[m] = rwg[m]; id[m] = m; sel[m] = 0; posmap[b * SS + m] = -1;
  }
  __syncthreads();
  // bitonic sort, final order: value desc, tie -> index asc (matches lax.top_k)
  for (int k = 2; k <= SS; k <<= 1)
    for (int j = k >> 1; j > 0; j >>= 1) {
      for (int t = tid; t < SS / 2; t += 1024) {
        int i = ((t & ~(j - 1)) << 1) | (t & (j - 1));
        int l = i | j;
        float vi = v[i], vl = v[l];
        int ii = id[i], il = id[l];
        bool lbi = (vl > vi) || (vl == vi && il < ii);   // l-elem before i-elem
        bool ibl = (vi > vl) || (vi == vl && ii < il);
        bool sw = ((i & k) == 0) ? lbi : ibl;
        if (sw) { v[i] = vl; v[l] = vi; id[i] = il; id[l] = ii; }
      }
      __syncthreads();
    }
  if (tid < CAP) { int s0 = id[tid]; sel[s0] = 1; seq2[tid] = s0; rank2[tid] = tid; }
  __syncthreads();
  // BCE loss: tgt=1 at selected
  float ls = 0.f;
  for (int m = tid; m < SS; m += 1024) {
    float r = rwg[m];
    float term = sel[m] ? logf(r) : log1pf(-r);
    ls += fmaxf(term, -100.f);
  }
#pragma unroll
  for (int off = 32; off > 0; off >>= 1) ls += __shfl_xor(ls, off, 64);
  if ((tid & 63) == 0) wsum[tid >> 6] = ls;
  __syncthreads();
  if (tid == 0) {
    float t = 0.f;
    for (int i = 0; i < 16; i++) t += wsum[i];
    atomicAdd(acc, t);
  }
  // sort (seq, rank) by seq asc -> idx_sorted, order
  for (int k = 2; k <= CAP; k <<= 1)
    for (int j = k >> 1; j > 0; j >>= 1) {
      __syncthreads();
      if (tid < CAP / 2) {
        int i = ((tid & ~(j - 1)) << 1) | (tid & (j - 1));
        int l = i | j;
        int si = seq2[i], sl = seq2[l];
        bool sw = ((i & k) == 0) ? (sl < si) : (si < sl);
        if (sw) {
          seq2[i] = sl; seq2[l] = si;
          int tr = rank2[i]; rank2[i] = rank2[l]; rank2[l] = tr;
        }
      }
    }
  __syncthreads();
  if (tid < CAP) {
    idxs[b * CAP + tid] = seq2[tid];
    wtop[b * CAP + tid] = rwg[rank2[tid]];          // faithful quirk
    posmap[b * SS + seq2[tid]] = b * CAP + tid;     // row -> compact slot
  }
}

__global__ void lossfin_kernel(const float* __restrict__ acc, float* __restrict__ out) {
  out[NOUT] = -acc[0] / (float)(BB * SS);
}

// ---------------- transpose f32 [R][C] -> bf16 [C][R] ----------------
__global__ void transpose_bf16_kernel(const float* __restrict__ in, ushort_t* __restrict__ out,
                                      int R, int C) {
  __shared__ float t[32][33];
  int c0 = blockIdx.x * 32, r0 = blockIdx.y * 32;
#pragma unroll
  for (int i = 0; i < 4; i++) {
    int y = threadIdx.y + i * 8;
    t[y][threadIdx.x] = in[(size_t)(r0 + y) * C + c0 + threadIdx.x];
  }
  __syncthreads();
#pragma unroll
  for (int i = 0; i < 4; i++) {
    int y = threadIdx.y + i * 8;
    out[(size_t)(c0 + y) * R + r0 + threadIdx.x] = f2bf(t[threadIdx.x][y]);
  }
}

// ---------------- gather selected rows of x -> bf16 A ----------------
__global__ void gather_kernel(const float* __restrict__ x, const int* __restrict__ idxs,
                              ushort_t* __restrict__ A) {
  int row = blockIdx.x;                 // [0, MTOT)
  int b = row >> 9;
  int seq = idxs[row];
  const float4* src = (const float4*)(x + ((size_t)(b * SS + seq)) * DD);
  float4 a = src[threadIdx.x];
  ushort4v o;
  o[0] = f2bf(a.x); o[1] = f2bf(a.y); o[2] = f2bf(a.z); o[3] = f2bf(a.w);
  *(ushort4v*)(A + (size_t)row * DD + threadIdx.x * 4) = o;
}

// ---------------- final scatter: out[row] = p>=0 ? O[p]*wtop[p] : 0 ----------------
__global__ void scatter_kernel(const float* __restrict__ O, const int* __restrict__ posmap,
                               const float* __restrict__ wtop, float* __restrict__ out) {
  int r = blockIdx.x;                   // [0, B*S)
  int p = posmap[r];
  float4 v = {0.f, 0.f, 0.f, 0.f};
  if (p >= 0) {
    float wt = wtop[p];
    v = ((const float4*)(O + (size_t)p * DD))[threadIdx.x];
    v.x *= wt; v.y *= wt; v.z *= wt; v.w *= wt;
  }
  ((float4*)(out + (size_t)r * DD))[threadIdx.x] = v;
}

// ---------------- GEMM: BM=256 x BN=128, BK=64, 8 waves, 8-phase fine interleave ----
// 3-buffer LDS rotation (K-tile t -> buf t%3), 2-ahead prefetch, counted vmcnt(6) at
// iteration top (never 0 mid-loop). 4 sub-phases per K-tile, each:
// {6 ds_read || 2 gld_lds -> s_barrier -> setprio(1) 8 MFMA setprio(0) -> s_barrier}.
// LDS: slot p of row r holds global k-slot p^(r&7) (inverse-swizzled SOURCE, linear
// gld_lds DEST; ds_read applies same XOR).
// MODE 0: epilogue gelu -> Hout bf16 [M][FF]
// MODE 1: epilogue raw atomicAdd into compact O f32 [MTOT][DD] (split-K via gridDim.z)
template <int MODE>
__global__ __launch_bounds__(512) void gemm_8p(const ushort_t* __restrict__ Ag,
                                               const ushort_t* __restrict__ Bg, int Kstride,
                                               ushort_t* __restrict__ Hout,
                                               float* __restrict__ Oacc) {
  __shared__ ushort_t lA[3][256 * 64];   // 96KB
  __shared__ ushort_t lB[3][128 * 64];   // 48KB
  const int tid = threadIdx.x;
  const int lane = tid & 63, wv = tid >> 6;
  const int wr = wv >> 1, wc = wv & 1;     // 4M x 2N wave grid, wave tile 64x64

  // bijective XCD swizzle (nwg == 256 for both launches)
  const int gx = gridDim.x, gy = gridDim.y;
  const int nwg = gx * gy * gridDim.z;
  int id = blockIdx.x + gx * (blockIdx.y + gy * blockIdx.z);
  int sw = (id & 7) * (nwg >> 3) + (id >> 3);
  const int bx = sw % gx;
  const int by = (sw / gx) % gy;
  const int bz = sw / (gx * gy);

  const int bm0 = by * 256, bn0 = bx * 128;
  const int kchunk = Kstride / gridDim.z;
  const int kbeg = bz * kchunk;
  const int nkt = kchunk / 64;             // 16 K-tiles for both GEMMs

  const int srow = lane >> 3;              // 0..7
  const int gslot = (lane & 7) ^ srow;     // inverse-swizzled global 16B slot

  float4v acc[4][4];
#pragma unroll
  for (int i = 0; i < 4; i++)
#pragma unroll
    for (int j = 0; j < 4; j++) acc[i][j] = (float4v){0.f, 0.f, 0.f, 0.f};

  // staging pieces: A rows 0-127 (2 loads), A rows 128-255 (2 loads), B (2 loads)
#define STAGE_A(buf, k0, half)                                                    \
  {                                                                               \
    _Pragma("unroll")                                                             \
    for (int i = 0; i < 2; i++) {                                                 \
      const int ii = (half) * 2 + i;                                              \
      const int chunkbase = ii * 512 + wv * 64;                                   \
      const int row = ii * 64 + wv * 8 + srow;                                    \
      const ushort_t* ga = Ag + (size_t)(bm0 + row) * Kstride + (k0) + gslot * 8; \
      GLD16(ga, &lA[buf][chunkbase * 8]);                                         \
    }                                                                             \
  }
#define STAGE_B(buf, k0)                                                          \
  {                                                                               \
    _Pragma("unroll")                                                             \
    for (int i = 0; i < 2; i++) {                                                 \
      const int chunkbase = i * 512 + wv * 64;                                    \
      const int row = i * 64 + wv * 8 + srow;                                     \
      const ushort_t* gb = Bg + (size_t)(bn0 + row) * Kstride + (k0) + gslot * 8; \
      GLD16(gb, &lB[buf][chunkbase * 8]);                                         \
    }                                                                             \
  }

  // prologue: K-tiles 0 and 1 in flight (12 loads/thread)
  STAGE_A(0, kbeg, 0); STAGE_A(0, kbeg, 1); STAGE_B(0, kbeg);
  STAGE_A(1, kbeg + 64, 0); STAGE_A(1, kbeg + 64, 1); STAGE_B(1, kbeg + 64);

  for (int t = 0; t < nkt; ++t) {
    const int c = t % 3;
    const int pb = (t + 2) % 3;
    const int kp = kbeg + (t + 2) * 64;
    const bool st = (t + 2) < nkt;
    // own-wave wait for K-tile t's 6 loads (t+1's may stay in flight), then publish
    if (t + 1 < nkt) { asm volatile("s_waitcnt vmcnt(6)" ::: "memory"); }
    else             { asm volatile("s_waitcnt vmcnt(0)" ::: "memory"); }
    __builtin_amdgcn_s_barrier();
#pragma unroll
    for (int q = 0; q < 4; ++q) {
      const int kk = q >> 1, mh = q & 1;
      const int s = (lane >> 4) + kk * 4;   // logical 16B k-slot 0..7
      short8v af[2], bfr[4];
#pragma unroll
      for (int m2 = 0; m2 < 2; m2++) {
        const int rr = wr * 64 + (mh * 2 + m2) * 16 + (lane & 15);
        af[m2] = *(const short8v*)&lA[c][rr * 64 + (s ^ (rr & 7)) * 8];
      }
#pragma unroll
      for (int nj = 0; nj < 4; nj++) {
        const int rr = wc * 64 + nj * 16 + (lane & 15);
        bfr[nj] = *(const short8v*)&lB[c][rr * 64 + (s ^ (rr & 7)) * 8];
      }
      if (st) {
        if (q == 0) STAGE_A(pb, kp, 0);
        if (q == 1) STAGE_A(pb, kp, 1);
        if (q == 2) STAGE_B(pb, kp);
      }
      __builtin_amdgcn_s_barrier();
      __builtin_amdgcn_s_setprio(1);
#pragma unroll
      for (int m2 = 0; m2 < 2; m2++)
#pragma unroll
        for (int nj = 0; nj < 4; nj++)
          acc[mh * 2 + m2][nj] =
              __builtin_amdgcn_mfma_f32_16x16x32_bf16(af[m2], bfr[nj], acc[mh * 2 + m2][nj], 0, 0, 0);
      __builtin_amdgcn_s_setprio(0);
      __builtin_amdgcn_s_barrier();
    }
  }
#undef STAGE_A
#undef STAGE_B

  if (MODE == 0) {
#pragma unroll
    for (int mi = 0; mi < 4; mi++) {
      int r0 = bm0 + wr * 64 + mi * 16 + ((lane >> 4) << 2);
#pragma unroll
      for (int nj = 0; nj < 4; nj++) {
        int cc = bn0 + wc * 64 + nj * 16 + (lane & 15);
#pragma unroll
        for (int r = 0; r < 4; r++) {
          float xv = acc[mi][nj][r];
          float g = 0.5f * xv * (1.f + tanhf(0.7978845608028654f * (xv + 0.044715f * xv * xv * xv)));
          Hout[(size_t)(r0 + r) * FF + cc] = f2bf(g);
        }
      }
    }
  } else {
#pragma unroll
    for (int mi = 0; mi < 4; mi++) {
      int tr0 = wr * 64 + mi * 16 + ((lane >> 4) << 2);
#pragma unroll
      for (int r = 0; r < 4; r++) {
        int grow = bm0 + tr0 + r;
        float* orow = Oacc + (size_t)grow * DD + bn0 + wc * 64 + (lane & 15);
#pragma unroll
        for (int nj = 0; nj < 4; nj++) atomicAdd(orow + nj * 16, acc[mi][nj][r]);
      }
    }
  }
}

extern "C" void kernel_launch(void* const* d_in, const int* in_sizes, int n_in,
                              void* d_out, int out_size, void* d_ws, size_t ws_size,
                              hipStream_t stream) {
  (void)in_sizes; (void)n_in; (void)out_size; (void)ws_size;
  const float* x  = (const float*)d_in[0];
  const float* wrt = (const float*)d_in[1];
  const float* W1 = (const float*)d_in[2];
  const float* W2 = (const float*)d_in[3];
  float* out = (float*)d_out;
  char* ws = (char*)d_ws;
  float*    rw   = (float*)(ws + OFF_RW);
  int*      idxs = (int*)(ws + OFF_IDX);
  float*    wtop = (float*)(ws + OFF_WTOP);
  float*    acc  = (float*)(ws + OFF_ACC);
  int*      posm = (int*)(ws + OFF_POS);
  ushort_t* A    = (ushort_t*)(ws + OFF_A);
  ushort_t* W1T  = (ushort_t*)(ws + OFF_W1T);
  ushort_t* W2T  = (ushort_t*)(ws + OFF_W2T);
  ushort_t* H    = (ushort_t*)(ws + OFF_H);
  float*    O    = (float*)(ws + OFF_W1T);   // overlays W1T (dead after GEMM1)

  hipMemsetAsync(acc, 0, 4, stream);
  router_kernel<<<dim3(BB * SS / 4), dim3(256), 0, stream>>>(x, wrt, rw);
  topk_kernel<<<dim3(BB), dim3(1024), 0, stream>>>(rw, idxs, wtop, posm, acc);
  lossfin_kernel<<<dim3(1), dim3(1), 0, stream>>>(acc, out);
  transpose_bf16_kernel<<<dim3(FF / 32, DD / 32), dim3(32, 8), 0, stream>>>(W1, W1T, DD, FF);
  transpose_bf16_kernel<<<dim3(DD / 32, FF / 32), dim3(32, 8), 0, stream>>>(W2, W2T, FF, DD);
  gather_kernel<<<dim3(MTOT), dim3(256), 0, stream>>>(x, idxs, A);
  // GEMM1: [2048x1024] * [4096x1024]^T -> gelu -> H   (grid 32x8 = 256 blocks)
  gemm_8p<0><<<dim3(FF / 128, MTOT / 256, 1), dim3(512), 0, stream>>>(A, W1T, DD, H, nullptr);
  // O overlays W1T: zero it after GEMM1, then GEMM2 accumulates (split-K=4, 8x8x4=256 blocks)
  hipMemsetAsync(O, 0, (size_t)MTOT * DD * 4, stream);
  gemm_8p<1><<<dim3(DD / 128, MTOT / 256, 4), dim3(512), 0, stream>>>(H, W2T, FF, nullptr, O);
  // final: every output row written exactly once (replaces 64MB memset + scatter)
  scatter_kernel<<<dim3(BB * SS), dim3(256), 0, stream>>>(O, posm, wtop, out);
}

// Round 7
// 202.111 us; speedup vs baseline: 1.0005x; 1.0005x over previous
//
#include <hip/hip_runtime.h>
#include <stdint.h>

#define BB 4
#define SS 4096
#define DD 1024
#define FF 4096
#define CAP 512
#define MTOT (BB*CAP)          // 2048
#define NOUT (BB*SS*DD)        // 16777216

typedef unsigned short ushort_t;
typedef float  float4v  __attribute__((ext_vector_type(4)));
typedef short  short8v  __attribute__((ext_vector_type(8)));
typedef unsigned short ushort4v __attribute__((ext_vector_type(4)));

// ws layout (bytes)
#define OFF_RW   0u             // B*S f32 = 64KB
#define OFF_IDX  (64u*1024u)    // 2048 int = 8KB
#define OFF_WTOP (72u*1024u)    // 2048 f32 = 8KB
#define OFF_ACC  (80u*1024u)    // 4B loss accumulator
#define OFF_POS  (128u*1024u)   // B*S int = 64KB (row -> compact slot or -1)
#define OFF_O    (5u<<20)       // MTOT*D f32 = 8MB (GEMM2 accumulator)
#define OFF_W2T  (13u<<20)      // D*F bf16 = 8MB (control: stays in ws)

// d_out staging layout (elements of ushort_t within the 64MB output buffer):
// A   [0,        2M)  = 4MB   (MTOT*DD bf16)
// W1T [2M,       6M)  = 8MB   (FF*DD bf16)
// H   [6M,      14M)  = 16MB  (MTOT*FF bf16)   -- all < 28MB < 64MB
// Final scatter + lossfin overwrite d_out completely every call.
#define DOUT_A_ELT   0u
#define DOUT_W1T_ELT (2u*1024u*1024u)
#define DOUT_H_ELT   (6u*1024u*1024u)

#define GLD16(gsrc, ldst) __builtin_amdgcn_global_load_lds( \
    (const __attribute__((address_space(1))) void*)(gsrc),  \
    (__attribute__((address_space(3))) void*)(ldst), 16, 0, 0)

__device__ inline ushort_t f2bf(float f) {
  uint32_t u = __builtin_bit_cast(uint32_t, f);
  u = u + 0x7fffu + ((u >> 16) & 1u);
  return (ushort_t)(u >> 16);
}

// ---------------- router: rw = sigmoid(x . w) ----------------
__global__ void router_kernel(const float* __restrict__ x, const float* __restrict__ w,
                              float* __restrict__ rw) {
  int wave = threadIdx.x >> 6;
  int lane = threadIdx.x & 63;
  int row  = blockIdx.x * 4 + wave;            // [0, B*S)
  const float4* xr = (const float4*)(x + (size_t)row * DD);
  const float4* wr = (const float4*)w;
  float s = 0.f;
#pragma unroll
  for (int i = 0; i < 4; i++) {
    float4 a = xr[lane + i * 64];
    float4 b = wr[lane + i * 64];
    s += a.x * b.x + a.y * b.y + a.z * b.z + a.w * b.w;
  }
#pragma unroll
  for (int off = 32; off > 0; off >>= 1) s += __shfl_xor(s, off, 64);
  if (lane == 0) rw[row] = 1.f / (1.f + expf(-s));
}

// ---------------- topk + order + w_top + posmap + BCE loss ----------------
__global__ __launch_bounds__(1024) void topk_kernel(const float* __restrict__ rw,
                                                    int* __restrict__ idxs,
                                                    float* __restrict__ wtop,
                                                    int* __restrict__ posmap,
                                                    float* __restrict__ acc) {
  __shared__ float v[SS];
  __shared__ int   id[SS];
  __shared__ int   seq2[CAP];
  __shared__ int   rank2[CAP];
  __shared__ unsigned char sel[SS];
  __shared__ float wsum[16];
  const int b = blockIdx.x, tid = threadIdx.x;
  const float* rwg = rw + (size_t)b * SS;
  for (int m = tid; m < SS; m += 1024) {
    v[m] = rwg[m]; id[m] = m; sel[m] = 0; posmap[b * SS + m] = -1;
  }
  __syncthreads();
  // bitonic sort, final order: value desc, tie -> index asc (matches lax.top_k)
  for (int k = 2; k <= SS; k <<= 1)
    for (int j = k >> 1; j > 0; j >>= 1) {
      for (int t = tid; t < SS / 2; t += 1024) {
        int i = ((t & ~(j - 1)) << 1) | (t & (j - 1));
        int l = i | j;
        float vi = v[i], vl = v[l];
        int ii = id[i], il = id[l];
        bool lbi = (vl > vi) || (vl == vi && il < ii);   // l-elem before i-elem
        bool ibl = (vi > vl) || (vi == vl && ii < il);
        bool sw = ((i & k) == 0) ? lbi : ibl;
        if (sw) { v[i] = vl; v[l] = vi; id[i] = il; id[l] = ii; }
      }
      __syncthreads();
    }
  if (tid < CAP) { int s0 = id[tid]; sel[s0] = 1; seq2[tid] = s0; rank2[tid] = tid; }
  __syncthreads();
  // BCE loss: tgt=1 at selected
  float ls = 0.f;
  for (int m = tid; m < SS; m += 1024) {
    float r = rwg[m];
    float term = sel[m] ? logf(r) : log1pf(-r);
    ls += fmaxf(term, -100.f);
  }
#pragma unroll
  for (int off = 32; off > 0; off >>= 1) ls += __shfl_xor(ls, off, 64);
  if ((tid & 63) == 0) wsum[tid >> 6] = ls;
  __syncthreads();
  if (tid == 0) {
    float t = 0.f;
    for (int i = 0; i < 16; i++) t += wsum[i];
    atomicAdd(acc, t);
  }
  // sort (seq, rank) by seq asc -> idx_sorted, order
  for (int k = 2; k <= CAP; k <<= 1)
    for (int j = k >> 1; j > 0; j >>= 1) {
      __syncthreads();
      if (tid < CAP / 2) {
        int i = ((tid & ~(j - 1)) << 1) | (tid & (j - 1));
        int l = i | j;
        int si = seq2[i], sl = seq2[l];
        bool sw = ((i & k) == 0) ? (sl < si) : (si < sl);
        if (sw) {
          seq2[i] = sl; seq2[l] = si;
          int tr = rank2[i]; rank2[i] = rank2[l]; rank2[l] = tr;
        }
      }
    }
  __syncthreads();
  if (tid < CAP) {
    idxs[b * CAP + tid] = seq2[tid];
    wtop[b * CAP + tid] = rwg[rank2[tid]];          // faithful quirk
    posmap[b * SS + seq2[tid]] = b * CAP + tid;     // row -> compact slot
  }
}

__global__ void lossfin_kernel(const float* __restrict__ acc, float* __restrict__ out) {
  out[NOUT] = -acc[0] / (float)(BB * SS);
}

// ---------------- transpose f32 [R][C] -> bf16 [C][R] ----------------
__global__ void transpose_bf16_kernel(const float* __restrict__ in, ushort_t* __restrict__ out,
                                      int R, int C) {
  __shared__ float t[32][33];
  int c0 = blockIdx.x * 32, r0 = blockIdx.y * 32;
#pragma unroll
  for (int i = 0; i < 4; i++) {
    int y = threadIdx.y + i * 8;
    t[y][threadIdx.x] = in[(size_t)(r0 + y) * C + c0 + threadIdx.x];
  }
  __syncthreads();
#pragma unroll
  for (int i = 0; i < 4; i++) {
    int y = threadIdx.y + i * 8;
    out[(size_t)(c0 + y) * R + r0 + threadIdx.x] = f2bf(t[threadIdx.x][y]);
  }
}

// ---------------- gather selected rows of x -> bf16 A ----------------
__global__ void gather_kernel(const float* __restrict__ x, const int* __restrict__ idxs,
                              ushort_t* __restrict__ A) {
  int row = blockIdx.x;                 // [0, MTOT)
  int b = row >> 9;
  int seq = idxs[row];
  const float4* src = (const float4*)(x + ((size_t)(b * SS + seq)) * DD);
  float4 a = src[threadIdx.x];
  ushort4v o;
  o[0] = f2bf(a.x); o[1] = f2bf(a.y); o[2] = f2bf(a.z); o[3] = f2bf(a.w);
  *(ushort4v*)(A + (size_t)row * DD + threadIdx.x * 4) = o;
}

// ---------------- final scatter: out[row] = p>=0 ? O[p]*wtop[p] : 0 ----------------
__global__ void scatter_kernel(const float* __restrict__ O, const int* __restrict__ posmap,
                               const float* __restrict__ wtop, float* __restrict__ out) {
  int r = blockIdx.x;                   // [0, B*S)
  int p = posmap[r];
  float4 v = {0.f, 0.f, 0.f, 0.f};
  if (p >= 0) {
    float wt = wtop[p];
    v = ((const float4*)(O + (size_t)p * DD))[threadIdx.x];
    v.x *= wt; v.y *= wt; v.z *= wt; v.w *= wt;
  }
  ((float4*)(out + (size_t)r * DD))[threadIdx.x] = v;
}

// ---------------- GEMM: BM=256 x BN=128, BK=64, 8 waves, 8-phase fine interleave ----
// (identical to round 6 — this round varies only operand PLACEMENT)
template <int MODE>
__global__ __launch_bounds__(512) void gemm_8p(const ushort_t* __restrict__ Ag,
                                               const ushort_t* __restrict__ Bg, int Kstride,
                                               ushort_t* __restrict__ Hout,
                                               float* __restrict__ Oacc) {
  __shared__ ushort_t lA[3][256 * 64];   // 96KB
  __shared__ ushort_t lB[3][128 * 64];   // 48KB
  const int tid = threadIdx.x;
  const int lane = tid & 63, wv = tid >> 6;
  const int wr = wv >> 1, wc = wv & 1;     // 4M x 2N wave grid, wave tile 64x64

  // bijective XCD swizzle (nwg == 256 for both launches)
  const int gx = gridDim.x, gy = gridDim.y;
  const int nwg = gx * gy * gridDim.z;
  int id = blockIdx.x + gx * (blockIdx.y + gy * blockIdx.z);
  int sw = (id & 7) * (nwg >> 3) + (id >> 3);
  const int bx = sw % gx;
  const int by = (sw / gx) % gy;
  const int bz = sw / (gx * gy);

  const int bm0 = by * 256, bn0 = bx * 128;
  const int kchunk = Kstride / gridDim.z;
  const int kbeg = bz * kchunk;
  const int nkt = kchunk / 64;             // 16 K-tiles for both GEMMs

  const int srow = lane >> 3;              // 0..7
  const int gslot = (lane & 7) ^ srow;     // inverse-swizzled global 16B slot

  float4v acc[4][4];
#pragma unroll
  for (int i = 0; i < 4; i++)
#pragma unroll
    for (int j = 0; j < 4; j++) acc[i][j] = (float4v){0.f, 0.f, 0.f, 0.f};

#define STAGE_A(buf, k0, half)                                                    \
  {                                                                               \
    _Pragma("unroll")                                                             \
    for (int i = 0; i < 2; i++) {                                                 \
      const int ii = (half) * 2 + i;                                              \
      const int chunkbase = ii * 512 + wv * 64;                                   \
      const int row = ii * 64 + wv * 8 + srow;                                    \
      const ushort_t* ga = Ag + (size_t)(bm0 + row) * Kstride + (k0) + gslot * 8; \
      GLD16(ga, &lA[buf][chunkbase * 8]);                                         \
    }                                                                             \
  }
#define STAGE_B(buf, k0)                                                          \
  {                                                                               \
    _Pragma("unroll")                                                             \
    for (int i = 0; i < 2; i++) {                                                 \
      const int chunkbase = i * 512 + wv * 64;                                    \
      const int row = i * 64 + wv * 8 + srow;                                     \
      const ushort_t* gb = Bg + (size_t)(bn0 + row) * Kstride + (k0) + gslot * 8; \
      GLD16(gb, &lB[buf][chunkbase * 8]);                                         \
    }                                                                             \
  }

  STAGE_A(0, kbeg, 0); STAGE_A(0, kbeg, 1); STAGE_B(0, kbeg);
  STAGE_A(1, kbeg + 64, 0); STAGE_A(1, kbeg + 64, 1); STAGE_B(1, kbeg + 64);

  for (int t = 0; t < nkt; ++t) {
    const int c = t % 3;
    const int pb = (t + 2) % 3;
    const int kp = kbeg + (t + 2) * 64;
    const bool st = (t + 2) < nkt;
    if (t + 1 < nkt) { asm volatile("s_waitcnt vmcnt(6)" ::: "memory"); }
    else             { asm volatile("s_waitcnt vmcnt(0)" ::: "memory"); }
    __builtin_amdgcn_s_barrier();
#pragma unroll
    for (int q = 0; q < 4; ++q) {
      const int kk = q >> 1, mh = q & 1;
      const int s = (lane >> 4) + kk * 4;   // logical 16B k-slot 0..7
      short8v af[2], bfr[4];
#pragma unroll
      for (int m2 = 0; m2 < 2; m2++) {
        const int rr = wr * 64 + (mh * 2 + m2) * 16 + (lane & 15);
        af[m2] = *(const short8v*)&lA[c][rr * 64 + (s ^ (rr & 7)) * 8];
      }
#pragma unroll
      for (int nj = 0; nj < 4; nj++) {
        const int rr = wc * 64 + nj * 16 + (lane & 15);
        bfr[nj] = *(const short8v*)&lB[c][rr * 64 + (s ^ (rr & 7)) * 8];
      }
      if (st) {
        if (q == 0) STAGE_A(pb, kp, 0);
        if (q == 1) STAGE_A(pb, kp, 1);
        if (q == 2) STAGE_B(pb, kp);
      }
      __builtin_amdgcn_s_barrier();
      __builtin_amdgcn_s_setprio(1);
#pragma unroll
      for (int m2 = 0; m2 < 2; m2++)
#pragma unroll
        for (int nj = 0; nj < 4; nj++)
          acc[mh * 2 + m2][nj] =
              __builtin_amdgcn_mfma_f32_16x16x32_bf16(af[m2], bfr[nj], acc[mh * 2 + m2][nj], 0, 0, 0);
      __builtin_amdgcn_s_setprio(0);
      __builtin_amdgcn_s_barrier();
    }
  }
#undef STAGE_A
#undef STAGE_B

  if (MODE == 0) {
#pragma unroll
    for (int mi = 0; mi < 4; mi++) {
      int r0 = bm0 + wr * 64 + mi * 16 + ((lane >> 4) << 2);
#pragma unroll
      for (int nj = 0; nj < 4; nj++) {
        int cc = bn0 + wc * 64 + nj * 16 + (lane & 15);
#pragma unroll
        for (int r = 0; r < 4; r++) {
          float xv = acc[mi][nj][r];
          float g = 0.5f * xv * (1.f + tanhf(0.7978845608028654f * (xv + 0.044715f * xv * xv * xv)));
          Hout[(size_t)(r0 + r) * FF + cc] = f2bf(g);
        }
      }
    }
  } else {
#pragma unroll
    for (int mi = 0; mi < 4; mi++) {
      int tr0 = wr * 64 + mi * 16 + ((lane >> 4) << 2);
#pragma unroll
      for (int r = 0; r < 4; r++) {
        int grow = bm0 + tr0 + r;
        float* orow = Oacc + (size_t)grow * DD + bn0 + wc * 64 + (lane & 15);
#pragma unroll
        for (int nj = 0; nj < 4; nj++) atomicAdd(orow + nj * 16, acc[mi][nj][r]);
      }
    }
  }
}

extern "C" void kernel_launch(void* const* d_in, const int* in_sizes, int n_in,
                              void* d_out, int out_size, void* d_ws, size_t ws_size,
                              hipStream_t stream) {
  (void)in_sizes; (void)n_in; (void)out_size; (void)ws_size;
  const float* x  = (const float*)d_in[0];
  const float* wrt = (const float*)d_in[1];
  const float* W1 = (const float*)d_in[2];
  const float* W2 = (const float*)d_in[3];
  float* out = (float*)d_out;
  char* ws = (char*)d_ws;
  float*    rw   = (float*)(ws + OFF_RW);
  int*      idxs = (int*)(ws + OFF_IDX);
  float*    wtop = (float*)(ws + OFF_WTOP);
  float*    acc  = (float*)(ws + OFF_ACC);
  int*      posm = (int*)(ws + OFF_POS);
  ushort_t* W2T  = (ushort_t*)(ws + OFF_W2T);   // control: GEMM2 B-operand in ws
  float*    O    = (float*)(ws + OFF_O);        // control: GEMM2 output in ws

  // EXPERIMENT: GEMM1 working set lives in d_out (scratch until final scatter)
  ushort_t* dob  = (ushort_t*)d_out;
  ushort_t* A    = dob + DOUT_A_ELT;
  ushort_t* W1T  = dob + DOUT_W1T_ELT;
  ushort_t* H    = dob + DOUT_H_ELT;

  hipMemsetAsync(acc, 0, 4, stream);
  router_kernel<<<dim3(BB * SS / 4), dim3(256), 0, stream>>>(x, wrt, rw);
  topk_kernel<<<dim3(BB), dim3(1024), 0, stream>>>(rw, idxs, wtop, posm, acc);
  transpose_bf16_kernel<<<dim3(FF / 32, DD / 32), dim3(32, 8), 0, stream>>>(W1, W1T, DD, FF);
  transpose_bf16_kernel<<<dim3(DD / 32, FF / 32), dim3(32, 8), 0, stream>>>(W2, W2T, FF, DD);
  gather_kernel<<<dim3(MTOT), dim3(256), 0, stream>>>(x, idxs, A);
  // GEMM1 (all operands in d_out): [2048x1024] * [4096x1024]^T -> gelu -> H
  gemm_8p<0><<<dim3(FF / 128, MTOT / 256, 1), dim3(512), 0, stream>>>(A, W1T, DD, H, nullptr);
  // GEMM2 (control, B-operand + output in ws): split-K=4, atomicAdd into O
  hipMemsetAsync(O, 0, (size_t)MTOT * DD * 4, stream);
  gemm_8p<1><<<dim3(DD / 128, MTOT / 256, 4), dim3(512), 0, stream>>>(H, W2T, FF, nullptr, O);
  // final: every d_out row written exactly once; loss element last
  scatter_kernel<<<dim3(BB * SS), dim3(256), 0, stream>>>(O, posm, wtop, out);
  lossfin_kernel<<<dim3(1), dim3(1), 0, stream>>>(acc, out);
}

// Round 8
// 188.031 us; speedup vs baseline: 1.0754x; 1.0749x over previous
//
#include <hip/hip_runtime.h>
#include <stdint.h>

#define BB 4
#define SS 4096
#define DD 1024
#define FF 4096
#define CAP 512
#define MTOT (BB*CAP)          // 2048
#define NOUT (BB*SS*DD)        // 16777216

typedef unsigned short ushort_t;
typedef float  float4v  __attribute__((ext_vector_type(4)));
typedef short  short8v  __attribute__((ext_vector_type(8)));
typedef unsigned short ushort4v __attribute__((ext_vector_type(4)));

// ws layout (bytes)
#define OFF_RW   0u             // B*S f32 = 64KB
#define OFF_IDX  (64u*1024u)    // 2048 int = 8KB
#define OFF_WTOP (72u*1024u)    // 2048 f32 = 8KB
#define OFF_ACC  (80u*1024u)    // 4B loss accumulator
#define OFF_POS  (128u*1024u)   // B*S int = 64KB (row -> compact slot or -1)
#define OFF_A    (1u<<20)       // MTOT*D bf16 = 4MB
#define OFF_W1T  (5u<<20)       // F*D bf16 = 8MB
#define OFF_W2T  (13u<<20)      // D*F bf16 = 8MB
#define OFF_H    (21u<<20)      // MTOT*F bf16 = 16MB
#define OFF_O    (37u<<20)      // MTOT*D f32 = 8MB (ends 45MB)

#define GLD16(gsrc, ldst) __builtin_amdgcn_global_load_lds( \
    (const __attribute__((address_space(1))) void*)(gsrc),  \
    (__attribute__((address_space(3))) void*)(ldst), 16, 0, 0)

__device__ inline ushort_t f2bf(float f) {
  uint32_t u = __builtin_bit_cast(uint32_t, f);
  u = u + 0x7fffu + ((u >> 16) & 1u);
  return (ushort_t)(u >> 16);
}

// ---------------- router: rw = sigmoid(x . w) ----------------
__global__ void router_kernel(const float* __restrict__ x, const float* __restrict__ w,
                              float* __restrict__ rw) {
  int wave = threadIdx.x >> 6;
  int lane = threadIdx.x & 63;
  int row  = blockIdx.x * 4 + wave;            // [0, B*S)
  const float4* xr = (const float4*)(x + (size_t)row * DD);
  const float4* wr = (const float4*)w;
  float s = 0.f;
#pragma unroll
  for (int i = 0; i < 4; i++) {
    float4 a = xr[lane + i * 64];
    float4 b = wr[lane + i * 64];
    s += a.x * b.x + a.y * b.y + a.z * b.z + a.w * b.w;
  }
#pragma unroll
  for (int off = 32; off > 0; off >>= 1) s += __shfl_xor(s, off, 64);
  if (lane == 0) rw[row] = 1.f / (1.f + expf(-s));
}

// ---------------- topk + order + w_top + posmap + BCE loss ----------------
__global__ __launch_bounds__(1024) void topk_kernel(const float* __restrict__ rw,
                                                    int* __restrict__ idxs,
                                                    float* __restrict__ wtop,
                                                    int* __restrict__ posmap,
                                                    float* __restrict__ acc) {
  __shared__ float v[SS];
  __shared__ int   id[SS];
  __shared__ int   seq2[CAP];
  __shared__ int   rank2[CAP];
  __shared__ unsigned char sel[SS];
  __shared__ float wsum[16];
  const int b = blockIdx.x, tid = threadIdx.x;
  const float* rwg = rw + (size_t)b * SS;
  for (int m = tid; m < SS; m += 1024) {
    v[m] = rwg[m]; id[m] = m; sel[m] = 0; posmap[b * SS + m] = -1;
  }
  __syncthreads();
  // bitonic sort, final order: value desc, tie -> index asc (matches lax.top_k)
  for (int k = 2; k <= SS; k <<= 1)
    for (int j = k >> 1; j > 0; j >>= 1) {
      for (int t = tid; t < SS / 2; t += 1024) {
        int i = ((t & ~(j - 1)) << 1) | (t & (j - 1));
        int l = i | j;
        float vi = v[i], vl = v[l];
        int ii = id[i], il = id[l];
        bool lbi = (vl > vi) || (vl == vi && il < ii);   // l-elem before i-elem
        bool ibl = (vi > vl) || (vi == vl && ii < il);
        bool sw = ((i & k) == 0) ? lbi : ibl;
        if (sw) { v[i] = vl; v[l] = vi; id[i] = il; id[l] = ii; }
      }
      __syncthreads();
    }
  if (tid < CAP) { int s0 = id[tid]; sel[s0] = 1; seq2[tid] = s0; rank2[tid] = tid; }
  __syncthreads();
  // BCE loss: tgt=1 at selected
  float ls = 0.f;
  for (int m = tid; m < SS; m += 1024) {
    float r = rwg[m];
    float term = sel[m] ? logf(r) : log1pf(-r);
    ls += fmaxf(term, -100.f);
  }
#pragma unroll
  for (int off = 32; off > 0; off >>= 1) ls += __shfl_xor(ls, off, 64);
  if ((tid & 63) == 0) wsum[tid >> 6] = ls;
  __syncthreads();
  if (tid == 0) {
    float t = 0.f;
    for (int i = 0; i < 16; i++) t += wsum[i];
    atomicAdd(acc, t);
  }
  // sort (seq, rank) by seq asc -> idx_sorted, order
  for (int k = 2; k <= CAP; k <<= 1)
    for (int j = k >> 1; j > 0; j >>= 1) {
      __syncthreads();
      if (tid < CAP / 2) {
        int i = ((tid & ~(j - 1)) << 1) | (tid & (j - 1));
        int l = i | j;
        int si = seq2[i], sl = seq2[l];
        bool sw = ((i & k) == 0) ? (sl < si) : (si < sl);
        if (sw) {
          seq2[i] = sl; seq2[l] = si;
          int tr = rank2[i]; rank2[i] = rank2[l]; rank2[l] = tr;
        }
      }
    }
  __syncthreads();
  if (tid < CAP) {
    idxs[b * CAP + tid] = seq2[tid];
    wtop[b * CAP + tid] = rwg[rank2[tid]];          // faithful quirk
    posmap[b * SS + seq2[tid]] = b * CAP + tid;     // row -> compact slot
  }
}

__global__ void lossfin_kernel(const float* __restrict__ acc, float* __restrict__ out) {
  out[NOUT] = -acc[0] / (float)(BB * SS);
}

// ---------------- transpose f32 [R][C] -> bf16 [C][R] ----------------
__global__ void transpose_bf16_kernel(const float* __restrict__ in, ushort_t* __restrict__ out,
                                      int R, int C) {
  __shared__ float t[32][33];
  int c0 = blockIdx.x * 32, r0 = blockIdx.y * 32;
#pragma unroll
  for (int i = 0; i < 4; i++) {
    int y = threadIdx.y + i * 8;
    t[y][threadIdx.x] = in[(size_t)(r0 + y) * C + c0 + threadIdx.x];
  }
  __syncthreads();
#pragma unroll
  for (int i = 0; i < 4; i++) {
    int y = threadIdx.y + i * 8;
    out[(size_t)(c0 + y) * R + r0 + threadIdx.x] = f2bf(t[threadIdx.x][y]);
  }
}

// ---------------- gather selected rows of x -> bf16 A ----------------
__global__ void gather_kernel(const float* __restrict__ x, const int* __restrict__ idxs,
                              ushort_t* __restrict__ A) {
  int row = blockIdx.x;                 // [0, MTOT)
  int b = row >> 9;
  int seq = idxs[row];
  const float4* src = (const float4*)(x + ((size_t)(b * SS + seq)) * DD);
  float4 a = src[threadIdx.x];
  ushort4v o;
  o[0] = f2bf(a.x); o[1] = f2bf(a.y); o[2] = f2bf(a.z); o[3] = f2bf(a.w);
  *(ushort4v*)(A + (size_t)row * DD + threadIdx.x * 4) = o;
}

// ---------------- final scatter: out[row] = p>=0 ? O[p]*wtop[p] : 0 ----------------
__global__ void scatter_kernel(const float* __restrict__ O, const int* __restrict__ posmap,
                               const float* __restrict__ wtop, float* __restrict__ out) {
  int r = blockIdx.x;                   // [0, B*S)
  int p = posmap[r];
  float4 v = {0.f, 0.f, 0.f, 0.f};
  if (p >= 0) {
    float wt = wtop[p];
    v = ((const float4*)(O + (size_t)p * DD))[threadIdx.x];
    v.x *= wt; v.y *= wt; v.z *= wt; v.w *= wt;
  }
  ((float4*)(out + (size_t)r * DD))[threadIdx.x] = v;
}

// ---------------- GEMM: BM=64 x BN=128, BK=64, 4 waves, m97 single-buffer loop ------
// Wave tile 32x64 (acc 2x4). 24KB LDS -> with 1024-block grids: 4 blocks/CU,
// 16 waves/CU — independent blocks hide each other's staging drains (m114).
// LDS: slot p of row r holds global k-slot p^(r&7) (inverse-swizzled SOURCE, linear
// gld_lds DEST; ds_read applies same XOR).
// MODE 0: epilogue gelu -> Hout bf16 [M][FF]
// MODE 1: epilogue raw atomicAdd into compact O f32 [MTOT][DD] (split-K via gridDim.z)
template <int MODE>
__global__ __launch_bounds__(256) void gemm_oc(const ushort_t* __restrict__ Ag,
                                               const ushort_t* __restrict__ Bg, int Kstride,
                                               ushort_t* __restrict__ Hout,
                                               float* __restrict__ Oacc) {
  __shared__ ushort_t lA[64 * 64];    // 8KB
  __shared__ ushort_t lB[128 * 64];   // 16KB
  const int tid = threadIdx.x;
  const int lane = tid & 63, wv = tid >> 6;
  const int wr = wv >> 1, wc = wv & 1;     // 2M x 2N wave grid, wave tile 32x64

  // bijective XCD swizzle (nwg == 1024 for both launches)
  const int gx = gridDim.x, gy = gridDim.y;
  const int nwg = gx * gy * gridDim.z;
  int id = blockIdx.x + gx * (blockIdx.y + gy * blockIdx.z);
  int sw = (id & 7) * (nwg >> 3) + (id >> 3);
  const int bx = sw % gx;
  const int by = (sw / gx) % gy;
  const int bz = sw / (gx * gy);

  const int bm0 = by * 64, bn0 = bx * 128;
  const int kchunk = Kstride / gridDim.z;
  const int kbeg = bz * kchunk;
  const int nkt = kchunk / 64;             // 16 K-tiles for both GEMMs

  const int srow = lane >> 3;              // 0..7
  const int gslot = (lane & 7) ^ srow;     // inverse-swizzled global 16B slot

  float4v acc[2][4];
#pragma unroll
  for (int i = 0; i < 2; i++)
#pragma unroll
    for (int j = 0; j < 4; j++) acc[i][j] = (float4v){0.f, 0.f, 0.f, 0.f};

  for (int t = 0; t < nkt; ++t) {
    const int k0 = kbeg + t * 64;
    __syncthreads();   // all waves done reading previous tile
#pragma unroll
    for (int i = 0; i < 2; i++) {          // A: 64 rows
      const int chunkbase = i * 256 + wv * 64;
      const int row = i * 32 + wv * 8 + srow;
      const ushort_t* ga = Ag + (size_t)(bm0 + row) * Kstride + k0 + gslot * 8;
      GLD16(ga, &lA[chunkbase * 8]);
    }
#pragma unroll
    for (int i = 0; i < 4; i++) {          // B: 128 rows
      const int chunkbase = i * 256 + wv * 64;
      const int row = i * 32 + wv * 8 + srow;
      const ushort_t* gb = Bg + (size_t)(bn0 + row) * Kstride + k0 + gslot * 8;
      GLD16(gb, &lB[chunkbase * 8]);
    }
    __syncthreads();   // compiler inserts vmcnt(0) drain; cross-block waves cover it
#pragma unroll
    for (int kk = 0; kk < 2; kk++) {
      const int s = (lane >> 4) + kk * 4;   // logical 16B k-slot 0..7
      short8v af[2], bfr[4];
#pragma unroll
      for (int mi = 0; mi < 2; mi++) {
        const int rr = wr * 32 + mi * 16 + (lane & 15);
        af[mi] = *(const short8v*)&lA[rr * 64 + (s ^ (rr & 7)) * 8];
      }
#pragma unroll
      for (int nj = 0; nj < 4; nj++) {
        const int rr = wc * 64 + nj * 16 + (lane & 15);
        bfr[nj] = *(const short8v*)&lB[rr * 64 + (s ^ (rr & 7)) * 8];
      }
#pragma unroll
      for (int mi = 0; mi < 2; mi++)
#pragma unroll
        for (int nj = 0; nj < 4; nj++)
          acc[mi][nj] = __builtin_amdgcn_mfma_f32_16x16x32_bf16(af[mi], bfr[nj], acc[mi][nj], 0, 0, 0);
    }
  }

  if (MODE == 0) {
#pragma unroll
    for (int mi = 0; mi < 2; mi++) {
      int r0 = bm0 + wr * 32 + mi * 16 + ((lane >> 4) << 2);
#pragma unroll
      for (int nj = 0; nj < 4; nj++) {
        int cc = bn0 + wc * 64 + nj * 16 + (lane & 15);
#pragma unroll
        for (int r = 0; r < 4; r++) {
          float xv = acc[mi][nj][r];
          float g = 0.5f * xv * (1.f + tanhf(0.7978845608028654f * (xv + 0.044715f * xv * xv * xv)));
          Hout[(size_t)(r0 + r) * FF + cc] = f2bf(g);
        }
      }
    }
  } else {
#pragma unroll
    for (int mi = 0; mi < 2; mi++) {
      int tr0 = bm0 + wr * 32 + mi * 16 + ((lane >> 4) << 2);
#pragma unroll
      for (int r = 0; r < 4; r++) {
        float* orow = Oacc + (size_t)(tr0 + r) * DD + bn0 + wc * 64 + (lane & 15);
#pragma unroll
        for (int nj = 0; nj < 4; nj++) atomicAdd(orow + nj * 16, acc[mi][nj][r]);
      }
    }
  }
}

extern "C" void kernel_launch(void* const* d_in, const int* in_sizes, int n_in,
                              void* d_out, int out_size, void* d_ws, size_t ws_size,
                              hipStream_t stream) {
  (void)in_sizes; (void)n_in; (void)out_size; (void)ws_size;
  const float* x  = (const float*)d_in[0];
  const float* wrt = (const float*)d_in[1];
  const float* W1 = (const float*)d_in[2];
  const float* W2 = (const float*)d_in[3];
  float* out = (float*)d_out;
  char* ws = (char*)d_ws;
  float*    rw   = (float*)(ws + OFF_RW);
  int*      idxs = (int*)(ws + OFF_IDX);
  float*    wtop = (float*)(ws + OFF_WTOP);
  float*    acc  = (float*)(ws + OFF_ACC);
  int*      posm = (int*)(ws + OFF_POS);
  ushort_t* A    = (ushort_t*)(ws + OFF_A);
  ushort_t* W1T  = (ushort_t*)(ws + OFF_W1T);
  ushort_t* W2T  = (ushort_t*)(ws + OFF_W2T);
  ushort_t* H    = (ushort_t*)(ws + OFF_H);
  float*    O    = (float*)(ws + OFF_O);

  hipMemsetAsync(acc, 0, 4, stream);
  hipMemsetAsync(O, 0, (size_t)MTOT * DD * 4, stream);
  router_kernel<<<dim3(BB * SS / 4), dim3(256), 0, stream>>>(x, wrt, rw);
  topk_kernel<<<dim3(BB), dim3(1024), 0, stream>>>(rw, idxs, wtop, posm, acc);
  transpose_bf16_kernel<<<dim3(FF / 32, DD / 32), dim3(32, 8), 0, stream>>>(W1, W1T, DD, FF);
  transpose_bf16_kernel<<<dim3(DD / 32, FF / 32), dim3(32, 8), 0, stream>>>(W2, W2T, FF, DD);
  gather_kernel<<<dim3(MTOT), dim3(256), 0, stream>>>(x, idxs, A);
  // GEMM1: [2048x1024]*[4096x1024]^T -> gelu -> H    grid (32,32)=1024 blocks, 4/CU
  gemm_oc<0><<<dim3(FF / 128, MTOT / 64, 1), dim3(256), 0, stream>>>(A, W1T, DD, H, nullptr);
  // GEMM2: [2048x4096]*[1024x4096]^T -> atomic O     grid (8,32,4)=1024 blocks, 4/CU
  gemm_oc<1><<<dim3(DD / 128, MTOT / 64, 4), dim3(256), 0, stream>>>(H, W2T, FF, nullptr, O);
  // final: every d_out row written exactly once; loss element last
  scatter_kernel<<<dim3(BB * SS), dim3(256), 0, stream>>>(O, posm, wtop, out);
  lossfin_kernel<<<dim3(1), dim3(1), 0, stream>>>(acc, out);
}

// Round 9
// 159.216 us; speedup vs baseline: 1.2700x; 1.1810x over previous
//
#include <hip/hip_runtime.h>
#include <stdint.h>

#define BB 4
#define SS 4096
#define DD 1024
#define FF 4096
#define CAP 512
#define MTOT (BB*CAP)          // 2048
#define NOUT (BB*SS*DD)        // 16777216

typedef unsigned short ushort_t;
typedef float  float4v  __attribute__((ext_vector_type(4)));
typedef short  short8v  __attribute__((ext_vector_type(8)));
typedef unsigned short ushort4v __attribute__((ext_vector_type(4)));

// ws layout (bytes)
#define OFF_RW   0u             // B*S f32 = 64KB
#define OFF_IDX  (64u*1024u)    // 2048 int = 8KB
#define OFF_WTOP (72u*1024u)    // 2048 f32 = 8KB
#define OFF_ACC  (80u*1024u)    // 4B loss accumulator
#define OFF_POS  (128u*1024u)   // B*S int = 64KB (row -> compact slot or -1)
#define OFF_RANK (256u*1024u)   // B*S int = 64KB (value-desc/index-asc rank)
#define OFF_A    (1u<<20)       // MTOT*D bf16 = 4MB
#define OFF_W1T  (5u<<20)       // F*D bf16 = 8MB
#define OFF_W2T  (13u<<20)      // D*F bf16 = 8MB
#define OFF_H    (21u<<20)      // MTOT*F bf16 = 16MB
#define OFF_O    (37u<<20)      // MTOT*D f32 = 8MB (ends 45MB)

#define GLD16(gsrc, ldst) __builtin_amdgcn_global_load_lds( \
    (const __attribute__((address_space(1))) void*)(gsrc),  \
    (__attribute__((address_space(3))) void*)(ldst), 16, 0, 0)

__device__ inline ushort_t f2bf(float f) {
  uint32_t u = __builtin_bit_cast(uint32_t, f);
  u = u + 0x7fffu + ((u >> 16) & 1u);
  return (ushort_t)(u >> 16);
}

// ---------------- router: rw = sigmoid(x . w) ----------------
__global__ void router_kernel(const float* __restrict__ x, const float* __restrict__ w,
                              float* __restrict__ rw) {
  int wave = threadIdx.x >> 6;
  int lane = threadIdx.x & 63;
  int row  = blockIdx.x * 4 + wave;            // [0, B*S)
  const float4* xr = (const float4*)(x + (size_t)row * DD);
  const float4* wr = (const float4*)w;
  float s = 0.f;
#pragma unroll
  for (int i = 0; i < 4; i++) {
    float4 a = xr[lane + i * 64];
    float4 b = wr[lane + i * 64];
    s += a.x * b.x + a.y * b.y + a.z * b.z + a.w * b.w;
  }
#pragma unroll
  for (int off = 32; off > 0; off >>= 1) s += __shfl_xor(s, off, 64);
  if (lane == 0) rw[row] = 1.f / (1.f + expf(-s));
}

// ---------------- rank: rank[i] = |{j: v_j>v_i or (v_j==v_i && j<i)}| ----------------
// grid (SS/64, BB), 256 threads: 4 threads per element, each scans a quarter of S.
__global__ __launch_bounds__(256) void rank_kernel(const float* __restrict__ rw,
                                                   int* __restrict__ rank) {
  __shared__ float v[SS];
  const int b = blockIdx.y;
  const float* rwg = rw + (size_t)b * SS;
  for (int m = threadIdx.x; m < SS / 4; m += 256)
    ((float4*)v)[m] = ((const float4*)rwg)[m];
  __syncthreads();
  const int e = blockIdx.x * 64 + (threadIdx.x >> 2);
  const int part = threadIdx.x & 3;
  const float vi = v[e];
  const int j0 = part * (SS / 4);
  int cnt = 0;
#pragma unroll 4
  for (int j4 = 0; j4 < SS / 16; ++j4) {
    float4 w = ((const float4*)(v + j0))[j4];
    int j = j0 + j4 * 4;
    cnt += (w.x > vi || (w.x == vi && (j + 0) < e));
    cnt += (w.y > vi || (w.y == vi && (j + 1) < e));
    cnt += (w.z > vi || (w.z == vi && (j + 2) < e));
    cnt += (w.w > vi || (w.w == vi && (j + 3) < e));
  }
  cnt += __shfl_xor(cnt, 1, 64);
  cnt += __shfl_xor(cnt, 2, 64);
  if (part == 0) rank[(size_t)b * SS + e] = cnt;
}

// ---------------- finalize: compact selected (rank<CAP) in index order ----------------
// 1 block/batch. idxs (asc), wtop = rw[rank] (faithful quirk), posmap, BCE loss.
__global__ __launch_bounds__(1024) void finalize_kernel(const float* __restrict__ rw,
                                                        const int* __restrict__ rank,
                                                        int* __restrict__ idxs,
                                                        float* __restrict__ wtop,
                                                        int* __restrict__ posmap,
                                                        float* __restrict__ acc) {
  __shared__ int   wsumI[16];
  __shared__ float wsumF[16];
  const int b = blockIdx.x, tid = threadIdx.x;
  const int lane = tid & 63, wv = tid >> 6;
  const float* rwg = rw + (size_t)b * SS;
  const int*   rkg = rank + (size_t)b * SS;
  const int m0 = tid * 4;
  int rk[4]; float rv[4];
  int cnt = 0;
#pragma unroll
  for (int u = 0; u < 4; u++) {
    rk[u] = rkg[m0 + u]; rv[u] = rwg[m0 + u];
    cnt += (rk[u] < CAP);
  }
  // wave inclusive scan of per-thread counts
  int val = cnt;
#pragma unroll
  for (int off = 1; off < 64; off <<= 1) {
    int n = __shfl_up(val, off, 64);
    if (lane >= off) val += n;
  }
  if (lane == 63) wsumI[wv] = val;
  __syncthreads();
  int wbase = 0;
  for (int w = 0; w < wv; ++w) wbase += wsumI[w];
  int excl = wbase + val - cnt;   // exclusive prefix for this thread
#pragma unroll
  for (int u = 0; u < 4; u++) {
    int m = m0 + u;
    if (rk[u] < CAP) {
      int pos = excl++;
      idxs[b * CAP + pos] = m;
      wtop[b * CAP + pos] = rwg[rk[u]];     // faithful quirk: rw at position rank (<CAP)
      posmap[(size_t)b * SS + m] = b * CAP + pos;
    } else {
      posmap[(size_t)b * SS + m] = -1;
    }
  }
  // BCE loss: tgt=1 at selected
  float ls = 0.f;
#pragma unroll
  for (int u = 0; u < 4; u++) {
    float term = (rk[u] < CAP) ? logf(rv[u]) : log1pf(-rv[u]);
    ls += fmaxf(term, -100.f);
  }
#pragma unroll
  for (int off = 32; off > 0; off >>= 1) ls += __shfl_xor(ls, off, 64);
  if (lane == 0) wsumF[wv] = ls;
  __syncthreads();
  if (tid == 0) {
    float t = 0.f;
    for (int i = 0; i < 16; i++) t += wsumF[i];
    atomicAdd(acc, t);
  }
}

__global__ void lossfin_kernel(const float* __restrict__ acc, float* __restrict__ out) {
  out[NOUT] = -acc[0] / (float)(BB * SS);
}

// ---------------- transpose f32 [R][C] -> bf16 [C][R] ----------------
__global__ void transpose_bf16_kernel(const float* __restrict__ in, ushort_t* __restrict__ out,
                                      int R, int C) {
  __shared__ float t[32][33];
  int c0 = blockIdx.x * 32, r0 = blockIdx.y * 32;
#pragma unroll
  for (int i = 0; i < 4; i++) {
    int y = threadIdx.y + i * 8;
    t[y][threadIdx.x] = in[(size_t)(r0 + y) * C + c0 + threadIdx.x];
  }
  __syncthreads();
#pragma unroll
  for (int i = 0; i < 4; i++) {
    int y = threadIdx.y + i * 8;
    out[(size_t)(c0 + y) * R + r0 + threadIdx.x] = f2bf(t[threadIdx.x][y]);
  }
}

// ---------------- gather selected rows of x -> bf16 A ----------------
__global__ void gather_kernel(const float* __restrict__ x, const int* __restrict__ idxs,
                              ushort_t* __restrict__ A) {
  int row = blockIdx.x;                 // [0, MTOT)
  int b = row >> 9;
  int seq = idxs[row];
  const float4* src = (const float4*)(x + ((size_t)(b * SS + seq)) * DD);
  float4 a = src[threadIdx.x];
  ushort4v o;
  o[0] = f2bf(a.x); o[1] = f2bf(a.y); o[2] = f2bf(a.z); o[3] = f2bf(a.w);
  *(ushort4v*)(A + (size_t)row * DD + threadIdx.x * 4) = o;
}

// ---------------- final scatter: out[row] = p>=0 ? O[p]*wtop[p] : 0 ----------------
__global__ void scatter_kernel(const float* __restrict__ O, const int* __restrict__ posmap,
                               const float* __restrict__ wtop, float* __restrict__ out) {
  int r = blockIdx.x;                   // [0, B*S)
  int p = posmap[r];
  float4 v = {0.f, 0.f, 0.f, 0.f};
  if (p >= 0) {
    float wt = wtop[p];
    v = ((const float4*)(O + (size_t)p * DD))[threadIdx.x];
    v.x *= wt; v.y *= wt; v.z *= wt; v.w *= wt;
  }
  ((float4*)(out + (size_t)r * DD))[threadIdx.x] = v;
}

// ---------------- GEMM: BM=64 x BN=128, BK=64, 4 waves, m97 single-buffer loop ------
// (unchanged from round 8 — 1024-block grids, 4 blocks/CU, 16 waves/CU)
template <int MODE>
__global__ __launch_bounds__(256) void gemm_oc(const ushort_t* __restrict__ Ag,
                                               const ushort_t* __restrict__ Bg, int Kstride,
                                               ushort_t* __restrict__ Hout,
                                               float* __restrict__ Oacc) {
  __shared__ ushort_t lA[64 * 64];    // 8KB
  __shared__ ushort_t lB[128 * 64];   // 16KB
  const int tid = threadIdx.x;
  const int lane = tid & 63, wv = tid >> 6;
  const int wr = wv >> 1, wc = wv & 1;     // 2M x 2N wave grid, wave tile 32x64

  // bijective XCD swizzle (nwg == 1024 for both launches)
  const int gx = gridDim.x, gy = gridDim.y;
  const int nwg = gx * gy * gridDim.z;
  int id = blockIdx.x + gx * (blockIdx.y + gy * blockIdx.z);
  int sw = (id & 7) * (nwg >> 3) + (id >> 3);
  const int bx = sw % gx;
  const int by = (sw / gx) % gy;
  const int bz = sw / (gx * gy);

  const int bm0 = by * 64, bn0 = bx * 128;
  const int kchunk = Kstride / gridDim.z;
  const int kbeg = bz * kchunk;
  const int nkt = kchunk / 64;             // 16 K-tiles for both GEMMs

  const int srow = lane >> 3;              // 0..7
  const int gslot = (lane & 7) ^ srow;     // inverse-swizzled global 16B slot

  float4v acc[2][4];
#pragma unroll
  for (int i = 0; i < 2; i++)
#pragma unroll
    for (int j = 0; j < 4; j++) acc[i][j] = (float4v){0.f, 0.f, 0.f, 0.f};

  for (int t = 0; t < nkt; ++t) {
    const int k0 = kbeg + t * 64;
    __syncthreads();   // all waves done reading previous tile
#pragma unroll
    for (int i = 0; i < 2; i++) {          // A: 64 rows
      const int chunkbase = i * 256 + wv * 64;
      const int row = i * 32 + wv * 8 + srow;
      const ushort_t* ga = Ag + (size_t)(bm0 + row) * Kstride + k0 + gslot * 8;
      GLD16(ga, &lA[chunkbase * 8]);
    }
#pragma unroll
    for (int i = 0; i < 4; i++) {          // B: 128 rows
      const int chunkbase = i * 256 + wv * 64;
      const int row = i * 32 + wv * 8 + srow;
      const ushort_t* gb = Bg + (size_t)(bn0 + row) * Kstride + k0 + gslot * 8;
      GLD16(gb, &lB[chunkbase * 8]);
    }
    __syncthreads();   // compiler inserts vmcnt(0) drain; cross-block waves cover it
#pragma unroll
    for (int kk = 0; kk < 2; kk++) {
      const int s = (lane >> 4) + kk * 4;   // logical 16B k-slot 0..7
      short8v af[2], bfr[4];
#pragma unroll
      for (int mi = 0; mi < 2; mi++) {
        const int rr = wr * 32 + mi * 16 + (lane & 15);
        af[mi] = *(const short8v*)&lA[rr * 64 + (s ^ (rr & 7)) * 8];
      }
#pragma unroll
      for (int nj = 0; nj < 4; nj++) {
        const int rr = wc * 64 + nj * 16 + (lane & 15);
        bfr[nj] = *(const short8v*)&lB[rr * 64 + (s ^ (rr & 7)) * 8];
      }
#pragma unroll
      for (int mi = 0; mi < 2; mi++)
#pragma unroll
        for (int nj = 0; nj < 4; nj++)
          acc[mi][nj] = __builtin_amdgcn_mfma_f32_16x16x32_bf16(af[mi], bfr[nj], acc[mi][nj], 0, 0, 0);
    }
  }

  if (MODE == 0) {
#pragma unroll
    for (int mi = 0; mi < 2; mi++) {
      int r0 = bm0 + wr * 32 + mi * 16 + ((lane >> 4) << 2);
#pragma unroll
      for (int nj = 0; nj < 4; nj++) {
        int cc = bn0 + wc * 64 + nj * 16 + (lane & 15);
#pragma unroll
        for (int r = 0; r < 4; r++) {
          float xv = acc[mi][nj][r];
          float g = 0.5f * xv * (1.f + tanhf(0.7978845608028654f * (xv + 0.044715f * xv * xv * xv)));
          Hout[(size_t)(r0 + r) * FF + cc] = f2bf(g);
        }
      }
    }
  } else {
#pragma unroll
    for (int mi = 0; mi < 2; mi++) {
      int tr0 = bm0 + wr * 32 + mi * 16 + ((lane >> 4) << 2);
#pragma unroll
      for (int r = 0; r < 4; r++) {
        float* orow = Oacc + (size_t)(tr0 + r) * DD + bn0 + wc * 64 + (lane & 15);
#pragma unroll
        for (int nj = 0; nj < 4; nj++) atomicAdd(orow + nj * 16, acc[mi][nj][r]);
      }
    }
  }
}

extern "C" void kernel_launch(void* const* d_in, const int* in_sizes, int n_in,
                              void* d_out, int out_size, void* d_ws, size_t ws_size,
                              hipStream_t stream) {
  (void)in_sizes; (void)n_in; (void)out_size; (void)ws_size;
  const float* x  = (const float*)d_in[0];
  const float* wrt = (const float*)d_in[1];
  const float* W1 = (const float*)d_in[2];
  const float* W2 = (const float*)d_in[3];
  float* out = (float*)d_out;
  char* ws = (char*)d_ws;
  float*    rw   = (float*)(ws + OFF_RW);
  int*      idxs = (int*)(ws + OFF_IDX);
  float*    wtop = (float*)(ws + OFF_WTOP);
  float*    acc  = (float*)(ws + OFF_ACC);
  int*      posm = (int*)(ws + OFF_POS);
  int*      rnk  = (int*)(ws + OFF_RANK);
  ushort_t* A    = (ushort_t*)(ws + OFF_A);
  ushort_t* W1T  = (ushort_t*)(ws + OFF_W1T);
  ushort_t* W2T  = (ushort_t*)(ws + OFF_W2T);
  ushort_t* H    = (ushort_t*)(ws + OFF_H);
  float*    O    = (float*)(ws + OFF_O);

  hipMemsetAsync(acc, 0, 4, stream);
  hipMemsetAsync(O, 0, (size_t)MTOT * DD * 4, stream);
  router_kernel<<<dim3(BB * SS / 4), dim3(256), 0, stream>>>(x, wrt, rw);
  rank_kernel<<<dim3(SS / 64, BB), dim3(256), 0, stream>>>(rw, rnk);
  finalize_kernel<<<dim3(BB), dim3(1024), 0, stream>>>(rw, rnk, idxs, wtop, posm, acc);
  transpose_bf16_kernel<<<dim3(FF / 32, DD / 32), dim3(32, 8), 0, stream>>>(W1, W1T, DD, FF);
  transpose_bf16_kernel<<<dim3(DD / 32, FF / 32), dim3(32, 8), 0, stream>>>(W2, W2T, FF, DD);
  gather_kernel<<<dim3(MTOT), dim3(256), 0, stream>>>(x, idxs, A);
  // GEMM1: [2048x1024]*[4096x1024]^T -> gelu -> H    grid (32,32)=1024 blocks, 4/CU
  gemm_oc<0><<<dim3(FF / 128, MTOT / 64, 1), dim3(256), 0, stream>>>(A, W1T, DD, H, nullptr);
  // GEMM2: [2048x4096]*[1024x4096]^T -> atomic O     grid (8,32,4)=1024 blocks, 4/CU
  gemm_oc<1><<<dim3(DD / 128, MTOT / 64, 4), dim3(256), 0, stream>>>(H, W2T, FF, nullptr, O);
  // final: every d_out row written exactly once; loss element last
  scatter_kernel<<<dim3(BB * SS), dim3(256), 0, stream>>>(O, posm, wtop, out);
  lossfin_kernel<<<dim3(1), dim3(1), 0, stream>>>(acc, out);
}